// Round 6
// baseline (255.007 us; speedup 1.0000x reference)
//
#include <hip/hip_runtime.h>
#include <hip/hip_bf16.h>

// Difference3DCostVolume: cost[b,c,d,h,w] = l[b,c,h,w] - r[b,c,h,w-d] (w>=d), else 1.0
// Shapes: B=4, C=32, H=96, W=312, D=48. Output [B,C,D,H,W] f32 = 736 MB -> write-bound.
//
// R6: one block per (bc, d) -> out slice is ONE contiguous 117 KB stream.
//  - d uniform per block => shifted row needs ONE staged copy: rs[m] = r_row[m-d].
//  - LDS [32 rows][312] is contiguous in item order: rs read = ds_read_b128 at
//    16*item; store & l-load = base + 4*item floats. All 16B-aligned. The by-d
//    misalignment lives only on the global staging loads (4B-aligned, L2-served).
//  - 3 chunks of 32 rows; LDS 39936 B -> 4 blocks/CU (2048 thr, 160 KB LDS).
//  - pad predicate via running w = (4*item) mod 312 (step 2048 ≡ 176 mod 312).
//  - XCD swizzle: all 48 d-blocks of a bc on one XCD -> inputs HBM-fetched once.

#define BB 4
#define CC 32
#define HH 96
#define WW 312
#define DD 48
#define SLICE (HH * WW)          // 29952 floats
#define NT 512
#define CH_ROWS 32
#define CH_FLOATS (CH_ROWS * WW) // 9984
#define CH_ITEMS (CH_FLOATS / 4) // 2496 float4 per chunk
#define NCHUNK (HH / CH_ROWS)    // 3
#define NBLOCKS (BB * CC * DD)   // 6144
#define WSTEP ((4 * NT) % WW)    // 176

typedef float float4u __attribute__((ext_vector_type(4), aligned(4)));
typedef float float4a __attribute__((ext_vector_type(4)));

__global__ __launch_bounds__(NT) void cost_volume_kernel(
    const float* __restrict__ l, const float* __restrict__ r,
    float* __restrict__ out) {
    // XCD-aware remap: dispatch round-robins XCDs by blockIdx, so fix xcd = blk%8;
    // give each XCD 16 bc-groups; within a group iterate d. (Perf-only; any
    // mapping is correct.)
    const int x = blockIdx.x & 7;
    const int q = blockIdx.x >> 3;          // 0..767
    const int bc = x + 8 * (q / DD);        // 0..127
    const int d = q % DD;                   // uniform per block
    const int tid = threadIdx.x;

    __shared__ float rs[CH_FLOATS];         // 39936 B

    const float* lslice = l + (size_t)bc * SLICE;
    const float* rslice = r + (size_t)bc * SLICE;
    float* oslice = out + ((size_t)bc * DD + d) * (size_t)SLICE;

    const int w0 = (4 * tid) % WW;          // first-lane w for item = tid
    const bool edge = (bc == 0);            // only bc==0,c==0 can underflow r

    for (int c = 0; c < NCHUNK; ++c) {
        if (c > 0) __syncthreads();         // rs still being read for chunk c-1

        // ---- stage rs[idx*4 + j] = r[bc, row, m - d] (garbage where m < d; unread)
        // linear source float offset = c*CH_FLOATS + 4*idx - d
        const float* rsl = rslice + c * CH_FLOATS - d;
        for (int idx = tid; idx < CH_ITEMS; idx += NT) {
            float4a v;
            if (edge && c == 0 && idx < 12) {          // 4*idx - d could be < 0
                #pragma unroll
                for (int j = 0; j < 4; ++j) {
                    const int g = 4 * idx + j - d;
                    v[j] = (g >= 0) ? rslice[g] : 0.0f;
                }
            } else {
                const float4u t = *reinterpret_cast<const float4u*>(rsl + 4 * idx);
                v = t;
            }
            reinterpret_cast<float4a*>(rs)[idx] = v;   // 16B-aligned ds_write
        }
        __syncthreads();

        // ---- emit: fully linear in item for l-load, rs-read, and store.
        const float* lc = lslice + c * CH_FLOATS;
        float* oc = oslice + c * CH_FLOATS;
        int w = w0;
        for (int item = tid; item < CH_ITEMS; item += NT) {
            const float4a a = *reinterpret_cast<const float4a*>(lc + 4 * item);
            const float4a b = reinterpret_cast<const float4a*>(rs)[item];
            float4a v;
            v.x = (w     >= d) ? (a.x - b.x) : 1.0f;
            v.y = (w + 1 >= d) ? (a.y - b.y) : 1.0f;
            v.z = (w + 2 >= d) ? (a.z - b.z) : 1.0f;
            v.w = (w + 3 >= d) ? (a.w - b.w) : 1.0f;
            *reinterpret_cast<float4a*>(oc + 4 * item) = v;
            w += WSTEP;
            if (w >= WW) w -= WW;           // w = (4*item) % WW, one subtract ok
        }
    }
}

extern "C" void kernel_launch(void* const* d_in, const int* in_sizes, int n_in,
                              void* d_out, int out_size, void* d_ws, size_t ws_size,
                              hipStream_t stream) {
    const float* l = (const float*)d_in[0];
    const float* r = (const float*)d_in[1];
    float* out = (float*)d_out;
    cost_volume_kernel<<<dim3(NBLOCKS), dim3(NT), 0, stream>>>(l, r, out);
}